// Round 1
// baseline (201.961 us; speedup 1.0000x reference)
//
#include <hip/hip_runtime.h>
#include <math.h>

#define D 64
#define MAXB 8  // LDS row-sum slots (actual B=4)

// ---------------- K1: zero out + row_sum ----------------
__global__ void k_init(float* __restrict__ out, float* __restrict__ row_sum, int total, int Bn) {
    int i = blockIdx.x * blockDim.x + threadIdx.x;
    if (i < total) out[i] = 0.f;
    if (i < Bn) row_sum[i] = 0.f;
}

// ---------------- K2: per-edge logits (one wave per edge) + segment-start marks ----------------
__global__ __launch_bounds__(256) void k_logits(
    const int* __restrict__ sel, const float* __restrict__ hc,
    const float* __restrict__ hu, const float* __restrict__ re,
    const float* __restrict__ wsm, const float* __restrict__ bias,
    const float* __restrict__ out_w, const float* __restrict__ out_b,
    float* __restrict__ logits, int* __restrict__ seg_start, int E)
{
    int e = blockIdx.x * 4 + (threadIdx.x >> 6);   // 4 waves per 256-thread block
    int d = threadIdx.x & 63;
    if (e >= E) return;
    const int* se = sel + (size_t)e * 8;
    int vi = se[1], vj = se[2], rel = se[3], idx_vi = se[4];
    int e2vi = se[6], e2vj = se[7];

    float hcvi = hc[(size_t)e2vi * D + d];
    float hcvj = hc[(size_t)e2vj * D + d];
    float huvi = hu[(size_t)vi * D + d];
    float huvj = hu[(size_t)vj * D + d];
    float r    = re[(size_t)rel * D + d];
    float hcvi_r = hcvi * r;   // matches (hc_vi*re) association in reference
    float huvi_r = huvi * r;

    float f = bias[d];
    f += wsm[0*D + d] * (hcvi   * hcvj);
    f += wsm[1*D + d] * (hcvi_r * hcvj);
    f += wsm[2*D + d] * (hcvi   * huvj);
    f += wsm[3*D + d] * (hcvi_r * huvj);
    f += wsm[4*D + d] * (huvi   * hcvj);
    f += wsm[5*D + d] * (huvi_r * hcvj);
    f += wsm[6*D + d] * (huvi   * huvj);
    f += wsm[7*D + d] * (huvi_r * huvj);
    f = fmaxf(f, 0.f) * out_w[d] + out_b[d];

    // wave-64 butterfly sum
    #pragma unroll
    for (int off = 32; off > 0; off >>= 1)
        f += __shfl_xor(f, off, 64);

    if (d == 0) {
        logits[e] = f;
        int prev = (e == 0) ? -1 : sel[(size_t)(e - 1) * 8 + 4];
        if (idx_vi != prev) seg_start[idx_vi] = e;  // idx_vi is nondecreasing -> contiguous runs
    }
}

// ---------------- K3: per-segment softmax + scatter-add into out, LDS row sums ----------------
__global__ __launch_bounds__(256) void k_softmax_scatter(
    const int* __restrict__ sel, const float* __restrict__ logits,
    const int* __restrict__ seg_start, const float* __restrict__ na,
    const float* __restrict__ edges_y, const int* __restrict__ n_vi_seg_p,
    float* __restrict__ out, float* __restrict__ row_sum, int E, int N, int Bn)
{
    __shared__ float rs[MAXB];
    if (threadIdx.x < MAXB) rs[threadIdx.x] = 0.f;
    __syncthreads();

    int s = blockIdx.x * blockDim.x + threadIdx.x;
    int nseg = *n_vi_seg_p;
    float local = 0.f;
    int idx = 0;
    if (s < nseg) {
        int start = seg_start[s];
        int end = (s + 1 < nseg) ? seg_start[s + 1] : E;
        const int* se0 = sel + (size_t)start * 8;
        idx = se0[0];
        int vi = se0[1];
        float na_e = na[(size_t)idx * N + vi];

        float m = -INFINITY;
        for (int e = start; e < end; ++e) m = fmaxf(m, logits[e]);
        float sum = 0.f;
        for (int e = start; e < end; ++e) sum += expf(logits[e] - m);
        for (int e = start; e < end; ++e) {
            float ev = expf(logits[e] - m);
            float trans = ev / sum;                      // e/es, same as reference
            float ta = na_e * trans * edges_y[e];
            int vj = sel[(size_t)e * 8 + 2];
            atomicAdd(out + (size_t)idx * N + vj, ta);
            local += ta;
        }
    }
    if (local != 0.f) atomicAdd(&rs[idx], local);
    __syncthreads();
    if (threadIdx.x < MAXB && threadIdx.x < Bn) {
        float v = rs[threadIdx.x];
        if (v != 0.f) atomicAdd(row_sum + threadIdx.x, v);
    }
}

// ---------------- K4: normalize rows ----------------
__global__ void k_norm(float* __restrict__ out, const float* __restrict__ row_sum, int total, int N) {
    int i = blockIdx.x * blockDim.x + threadIdx.x;
    if (i < total) out[i] = out[i] / row_sum[i / N];
}

extern "C" void kernel_launch(void* const* d_in, const int* in_sizes, int n_in,
                              void* d_out, int out_size, void* d_ws, size_t ws_size,
                              hipStream_t stream)
{
    const float* na    = (const float*)d_in[0];   // (B,N)
    const int*   sel   = (const int*)  d_in[1];   // (E,8)
    const float* ey    = (const float*)d_in[2];   // (E,)
    const float* hc    = (const float*)d_in[3];   // (n_visited, D)
    const float* hu    = (const float*)d_in[4];   // (1,N,D)
    const float* re    = (const float*)d_in[5];   // (R,D)
    const float* wsm   = (const float*)d_in[6];   // (8,D)
    const float* bias  = (const float*)d_in[7];   // (D,)
    const float* ow    = (const float*)d_in[8];   // (D,)
    const float* ob    = (const float*)d_in[9];   // (D,)
    const int* n_vi_seg_p = (const int*)d_in[10]; // scalar
    // d_in[11] = n_vj_seg (unused: idx_vj segmentation collapses to direct scatter)

    float* out = (float*)d_out;

    const int E = in_sizes[2];
    const int N = in_sizes[4] / D;    // hidden_uncon = N*D
    const int Bn = in_sizes[0] / N;   // node_attention = B*N
    const int BN = in_sizes[0];

    // workspace: logits (E floats) | seg_start (E ints) | row_sum (B floats)
    float* logits    = (float*)d_ws;
    int*   seg_start = (int*)  ((char*)d_ws + (size_t)E * 4);
    float* row_sum   = (float*)((char*)d_ws + (size_t)E * 8);

    k_init<<<(BN + 255) / 256, 256, 0, stream>>>(out, row_sum, BN, Bn);
    k_logits<<<(E + 3) / 4, 256, 0, stream>>>(sel, hc, hu, re, wsm, bias, ow, ob,
                                              logits, seg_start, E);
    k_softmax_scatter<<<(E + 255) / 256, 256, 0, stream>>>(sel, logits, seg_start, na, ey,
                                                           n_vi_seg_p, out, row_sum, E, N, Bn);
    k_norm<<<(BN + 255) / 256, 256, 0, stream>>>(out, row_sum, BN, N);
}

// Round 2
// 189.849 us; speedup vs baseline: 1.0638x; 1.0638x over previous
//
#include <hip/hip_runtime.h>
#include <math.h>

#define D 64

// ---------------- K2: logits (16 lanes x float4 per edge, 4 edges/wave) ----------------
// Also zeroes out[] and row_sum[] in its prologue (consumed only by later kernels).
__global__ __launch_bounds__(256) void k_logits(
    const int* __restrict__ sel, const float* __restrict__ hc,
    const float* __restrict__ hu, const float* __restrict__ re,
    const float* __restrict__ wsm, const float* __restrict__ bias,
    const float* __restrict__ out_w, const float* __restrict__ out_b,
    float* __restrict__ logits, int* __restrict__ seg_start,
    float* __restrict__ out, float* __restrict__ row_sum,
    int E, int BN, int Bn)
{
    const int tid = blockIdx.x * 256 + threadIdx.x;
    const int nthreads = gridDim.x * 256;

    // prologue: zero output + row sums (used by K3/K4; kernel boundary orders it)
    for (int i = tid; i < BN; i += nthreads) out[i] = 0.f;
    if (tid < Bn) row_sum[tid] = 0.f;

    const int lane = threadIdx.x & 63;
    const int g    = lane >> 4;    // edge-group within wave (0..3)
    const int d16  = lane & 15;    // lane within group; covers d = d16*4 .. d16*4+3

    // hoist constants into registers (amortized over grid-stride loop)
    const float4* wsm4 = (const float4*)wsm;
    float4 W[8];
    #pragma unroll
    for (int k = 0; k < 8; ++k) W[k] = wsm4[k * 16 + d16];
    const float4 Bv = ((const float4*)bias)[d16];
    const float4 Ow = ((const float4*)out_w)[d16];
    const float4 Ob = ((const float4*)out_b)[d16];
    const float* Wf  = (const float*)W;
    const float* Bvf = (const float*)&Bv;
    const float* Owf = (const float*)&Ow;
    const float* Obf = (const float*)&Ob;

    const float4* hc4 = (const float4*)hc;
    const float4* hu4 = (const float4*)hu;
    const float4* re4 = (const float4*)re;

    const int wave   = tid >> 6;
    const int nwaves = nthreads >> 6;
    const int quads  = (E + 3) >> 2;

    for (int q = wave; q < quads; q += nwaves) {
        const int e = q * 4 + g;
        const bool valid = (e < E);
        const int ec = valid ? e : (E - 1);

        const int4 seA = *(const int4*)(sel + (size_t)ec * 8);     // idx, vi, vj, rel
        const int4 seB = *(const int4*)(sel + (size_t)ec * 8 + 4); // idx_vi, idx_vj, e2vi, e2vj

        const float4 a  = hc4[(size_t)seB.z * 16 + d16];  // hc_vi
        const float4 c  = hc4[(size_t)seB.w * 16 + d16];  // hc_vj
        const float4 ui = hu4[(size_t)seA.y * 16 + d16];  // hu_vi
        const float4 uj = hu4[(size_t)seA.z * 16 + d16];  // hu_vj
        const float4 r  = re4[(size_t)seA.w * 16 + d16];  // rel_emb

        const float* ap  = (const float*)&a;
        const float* cp  = (const float*)&c;
        const float* uip = (const float*)&ui;
        const float* ujp = (const float*)&uj;
        const float* rp  = (const float*)&r;

        float acc = 0.f;
        #pragma unroll
        for (int k4 = 0; k4 < 4; ++k4) {
            const float hcvi = ap[k4], hcvj = cp[k4];
            const float huvi = uip[k4], huvj = ujp[k4];
            const float rr = rp[k4];
            const float hcr = hcvi * rr;   // (hc_vi*re) association as in reference
            const float hur = huvi * rr;
            float f = Bvf[k4];
            f += Wf[0 * 4 + k4] * (hcvi * hcvj);
            f += Wf[1 * 4 + k4] * (hcr  * hcvj);
            f += Wf[2 * 4 + k4] * (hcvi * huvj);
            f += Wf[3 * 4 + k4] * (hcr  * huvj);
            f += Wf[4 * 4 + k4] * (huvi * hcvj);
            f += Wf[5 * 4 + k4] * (hur  * hcvj);
            f += Wf[6 * 4 + k4] * (huvi * huvj);
            f += Wf[7 * 4 + k4] * (hur  * huvj);
            f = fmaxf(f, 0.f) * Owf[k4] + Obf[k4];
            acc += f;
        }

        // reduce across the 16 lanes of this group (offsets stay within group)
        #pragma unroll
        for (int off = 8; off > 0; off >>= 1)
            acc += __shfl_xor(acc, off, 64);

        // previous edge's idx_vi from the neighboring group (valid for g>0)
        const int idxvi = seB.x;
        const int src = (lane >= 16) ? (lane - 16) : lane;
        const int prevwave = __shfl(idxvi, src, 64);

        if (d16 == 0 && valid) {
            logits[e] = acc;
            int prev;
            if (e == 0)      prev = -1;
            else if (g == 0) prev = sel[(size_t)(e - 1) * 8 + 4];
            else             prev = prevwave;
            if (idxvi != prev) seg_start[idxvi] = e;  // idx_vi nondecreasing -> runs
        }
    }
}

// ---------------- K3: per-segment softmax + scatter-add + row sums ----------------
__global__ __launch_bounds__(256) void k_softmax_scatter(
    const int* __restrict__ sel, const float* __restrict__ logits,
    const int* __restrict__ seg_start, const float* __restrict__ na,
    const float* __restrict__ edges_y, const int* __restrict__ n_vi_seg_p,
    float* __restrict__ out, float* __restrict__ row_sum, int E, int N)
{
    const int s = blockIdx.x * 256 + threadIdx.x;
    const int nseg = *n_vi_seg_p;
    float local = 0.f;
    int idx = 0;
    if (s < nseg) {
        const int start = seg_start[s];
        const int end = (s + 1 < nseg) ? seg_start[s + 1] : E;
        const int4 h = *(const int4*)(sel + (size_t)start * 8);
        idx = h.x;
        const int vi = h.y;
        const float na_e = na[(size_t)idx * N + vi];

        float m = logits[start];
        for (int e = start + 1; e < end; ++e) m = fmaxf(m, logits[e]);
        float sum = 0.f;
        for (int e = start; e < end; ++e) sum += __expf(logits[e] - m);
        const float scale = na_e / sum;
        for (int e = start; e < end; ++e) {
            const float ta = scale * __expf(logits[e] - m) * edges_y[e];
            const int vj = sel[(size_t)e * 8 + 2];
            atomicAdd(out + (size_t)idx * N + vj, ta);
            local += ta;
        }
    }

    // per-batch row-sum reduction: fast path when the wave is idx-uniform
    const int first = __shfl(idx, 0, 64);
    if (__all(idx == first)) {
        float v = local;
        #pragma unroll
        for (int off = 32; off > 0; off >>= 1)
            v += __shfl_xor(v, off, 64);
        if ((threadIdx.x & 63) == 0 && v != 0.f) atomicAdd(row_sum + first, v);
    } else {
        if (local != 0.f) atomicAdd(row_sum + idx, local);
    }
}

// ---------------- K4: normalize rows (2D grid, no integer divide) ----------------
__global__ void k_norm(float* __restrict__ out, const float* __restrict__ row_sum, int N) {
    const int col = blockIdx.x * blockDim.x + threadIdx.x;
    const int row = blockIdx.y;
    if (col < N) {
        const size_t i = (size_t)row * N + col;
        out[i] = out[i] / row_sum[row];
    }
}

extern "C" void kernel_launch(void* const* d_in, const int* in_sizes, int n_in,
                              void* d_out, int out_size, void* d_ws, size_t ws_size,
                              hipStream_t stream)
{
    const float* na    = (const float*)d_in[0];   // (B,N)
    const int*   sel   = (const int*)  d_in[1];   // (E,8)
    const float* ey    = (const float*)d_in[2];   // (E,)
    const float* hc    = (const float*)d_in[3];   // (n_visited, D)
    const float* hu    = (const float*)d_in[4];   // (1,N,D)
    const float* re    = (const float*)d_in[5];   // (R,D)
    const float* wsm   = (const float*)d_in[6];   // (8,D)
    const float* bias  = (const float*)d_in[7];   // (D,)
    const float* ow    = (const float*)d_in[8];   // (D,)
    const float* ob    = (const float*)d_in[9];   // (D,)
    const int* n_vi_seg_p = (const int*)d_in[10]; // scalar
    // d_in[11] = n_vj_seg (unused: idx_vj segmentation collapses to direct scatter)

    float* out = (float*)d_out;

    const int E  = in_sizes[2];
    const int N  = in_sizes[4] / D;   // hidden_uncon = N*D
    const int BN = in_sizes[0];       // B*N
    const int Bn = BN / N;

    // workspace: logits (E floats) | seg_start (E ints) | row_sum (B floats)
    float* logits    = (float*)d_ws;
    int*   seg_start = (int*)  ((char*)d_ws + (size_t)E * 4);
    float* row_sum   = (float*)((char*)d_ws + (size_t)E * 8);

    k_logits<<<2048, 256, 0, stream>>>(sel, hc, hu, re, wsm, bias, ow, ob,
                                       logits, seg_start, out, row_sum, E, BN, Bn);
    k_softmax_scatter<<<(E + 255) / 256, 256, 0, stream>>>(sel, logits, seg_start, na, ey,
                                                           n_vi_seg_p, out, row_sum, E, N);
    dim3 ngrid((N + 255) / 256, Bn);
    k_norm<<<ngrid, 256, 0, stream>>>(out, row_sum, N);
}